// Round 1
// baseline (176.702 us; speedup 1.0000x reference)
//
#include <hip/hip_runtime.h>

// out[l, k] = sum_{s : Q[items[l], s] == 1} E[user, s, k]
// SKILL_NUM = 256, K_HIDDEN = 128 fixed; L derived from in_sizes.
//
// One wave (64 lanes) per sequence position l. Each lane owns output
// columns {lane, lane+64}. Active skills found via 4 x __ballot over the
// 256-entry Q row; the resulting 64-bit masks are wave-uniform, so the
// bit-scan accumulation loop is divergence-free and needs no LDS/sync.

#define SKILL_NUM 256
#define K_HIDDEN  128

__global__ __launch_bounds__(256) void item_emb_kernel(
    const int*   __restrict__ user_p,   // [1]
    const float* __restrict__ Q,        // [N_ITEMS, 256]
    const int*   __restrict__ items,    // [L]
    const float* __restrict__ E_all,    // [USER_NUM, 256, 128]
    float*       __restrict__ out,      // [L, 128]
    int L)
{
    const int wave = threadIdx.x >> 6;            // 0..3
    const int lane = threadIdx.x & 63;
    const int l    = blockIdx.x * 4 + wave;       // sequence position
    if (l >= L) return;

    const int item = items[l];                     // wave-uniform broadcast load
    const float* __restrict__ qrow = Q + (size_t)item * SKILL_NUM;
    const float* __restrict__ E =
        E_all + (size_t)user_p[0] * (SKILL_NUM * K_HIDDEN);

    float acc0 = 0.0f;   // column = lane
    float acc1 = 0.0f;   // column = lane + 64

    #pragma unroll
    for (int c = 0; c < SKILL_NUM / 64; ++c) {
        const float qv = qrow[c * 64 + lane];              // coalesced 256 B
        unsigned long long mask = __ballot(qv != 0.0f);    // wave-uniform
        while (mask) {
            const int s = c * 64 + __builtin_ctzll(mask);  // uniform skill idx
            mask &= mask - 1;
            const float* __restrict__ erow = E + (size_t)s * K_HIDDEN;
            acc0 += erow[lane];                            // coalesced 256 B
            acc1 += erow[lane + 64];                       // coalesced 256 B
        }
    }

    float* __restrict__ orow = out + (size_t)l * K_HIDDEN;
    orow[lane]      = acc0;
    orow[lane + 64] = acc1;
}

extern "C" void kernel_launch(void* const* d_in, const int* in_sizes, int n_in,
                              void* d_out, int out_size, void* d_ws, size_t ws_size,
                              hipStream_t stream) {
    const int*   user_p = (const int*)  d_in[0];
    const float* Q      = (const float*)d_in[1];
    const int*   items  = (const int*)  d_in[2];
    const float* E_all  = (const float*)d_in[3];
    float*       out    = (float*)      d_out;

    const int L = in_sizes[2];                 // SEQ_LEN (8192)
    const int blocks = (L + 3) / 4;            // 4 positions (waves) per block

    item_emb_kernel<<<blocks, 256, 0, stream>>>(user_p, Q, items, E_all, out, L);
}

// Round 2
// 174.731 us; speedup vs baseline: 1.0113x; 1.0113x over previous
//
#include <hip/hip_runtime.h>

// out[l, k] = sum_{s : Q[items[l], s] == 1} E[user, s, k]
// SKILL_NUM = 256, K_HIDDEN = 128 fixed; L from in_sizes.
//
// One wave per sequence position. Lane owns output cols {2*lane, 2*lane+1}
// (float2). Active skills via 4 hoisted __ballot's (wave-uniform 64-bit
// masks). Scan loop processes 2 skills per iteration so two
// global_load_dwordx2 are in flight before the dependent accumulate —
// halves the exposed L2 round-trips vs one-skill-per-iter.

#define SKILL_NUM 256
#define K_HIDDEN  128

__global__ __launch_bounds__(256) void item_emb_kernel(
    const int*   __restrict__ user_p,   // [1]
    const float* __restrict__ Q,        // [N_ITEMS, 256]
    const int*   __restrict__ items,    // [L]
    const float* __restrict__ E_all,    // [USER_NUM, 256, 128]
    float*       __restrict__ out,      // [L, 128]
    int L)
{
    const int wave = threadIdx.x >> 6;
    const int lane = threadIdx.x & 63;
    const int l    = blockIdx.x * 4 + wave;
    if (l >= L) return;

    const int item = items[l];                         // wave-uniform
    const float* __restrict__ qrow = Q + (size_t)item * SKILL_NUM;
    const float2* __restrict__ E2 = (const float2*)(
        E_all + (size_t)user_p[0] * (SKILL_NUM * K_HIDDEN));

    // Hoist all 4 Q-chunk loads + ballots; masks are wave-uniform scalars.
    const float q0 = qrow[lane];
    const float q1 = qrow[64 + lane];
    const float q2 = qrow[128 + lane];
    const float q3 = qrow[192 + lane];
    unsigned long long m0 = __ballot(q0 != 0.0f);
    unsigned long long m1 = __ballot(q1 != 0.0f);
    unsigned long long m2 = __ballot(q2 != 0.0f);
    unsigned long long m3 = __ballot(q3 != 0.0f);

    float ax = 0.0f, ay = 0.0f;

    auto scan = [&](unsigned long long mask, int base) {
        while (mask) {
            const int s0 = base + __builtin_ctzll(mask);
            mask &= mask - 1;
            if (mask) {                                 // wave-uniform branch
                const int s1 = base + __builtin_ctzll(mask);
                mask &= mask - 1;
                const float2 a = E2[(size_t)s0 * 64 + lane];  // dwordx2, 512 B/wave
                const float2 b = E2[(size_t)s1 * 64 + lane];  // in flight together
                ax += a.x + b.x;
                ay += a.y + b.y;
            } else {
                const float2 a = E2[(size_t)s0 * 64 + lane];
                ax += a.x;
                ay += a.y;
            }
        }
    };
    scan(m0, 0);
    scan(m1, 64);
    scan(m2, 128);
    scan(m3, 192);

    float2 r;
    r.x = ax;
    r.y = ay;
    ((float2*)out)[(size_t)l * 64 + lane] = r;          // dwordx2 store
}

extern "C" void kernel_launch(void* const* d_in, const int* in_sizes, int n_in,
                              void* d_out, int out_size, void* d_ws, size_t ws_size,
                              hipStream_t stream) {
    const int*   user_p = (const int*)  d_in[0];
    const float* Q      = (const float*)d_in[1];
    const int*   items  = (const int*)  d_in[2];
    const float* E_all  = (const float*)d_in[3];
    float*       out    = (float*)      d_out;

    const int L = in_sizes[2];                 // SEQ_LEN (8192)
    const int blocks = (L + 3) / 4;            // 4 positions (waves) per block

    item_emb_kernel<<<blocks, 256, 0, stream>>>(user_p, Q, items, E_all, out, L);
}